// Round 3
// baseline (225.719 us; speedup 1.0000x reference)
//
#include <hip/hip_runtime.h>
#include <hip/hip_bf16.h>
#include <hip/hip_fp16.h>

#define D 64
#define KPER 20

typedef __attribute__((ext_vector_type(8))) short short8;
typedef __attribute__((ext_vector_type(4))) float floatx4;

__device__ __forceinline__ unsigned short f2bfu(float x) {
    __hip_bfloat16 h = __float2bfloat16(x);
    return *reinterpret_cast<unsigned short*>(&h);
}
// f16 bits (tables are f16: 3 more mantissa bits than bf16 AND enables v_pk_* math)
__device__ __forceinline__ unsigned short f2hu(float x) {
    __half h = __float2half(x);
    return *reinterpret_cast<unsigned short*>(&h);
}
union UH2 { unsigned u; __half2 h; };
__device__ __forceinline__ __half2 u2h2(unsigned u) { UH2 x; x.u = u; return x.h; }

// guaranteed-available packed f16 max (avoid header-version-dependent __hmax2)
__device__ __forceinline__ __half2 pk_max(__half2 a, __half2 b) {
    __half2 r;
    asm("v_pk_max_f16 %0, %1, %2" : "=v"(r) : "v"(a), "v"(b));
    return r;
}

__device__ __forceinline__ float fast_tanh(float x) {
    float xc = fminf(fmaxf(x, -15.f), 15.f);
    float e = __expf(2.f * xc);
    return 1.f - 2.f * __builtin_amdgcn_rcpf(1.f + e);
}

// ---- DPP reductions (VALU pipe) ----------------------------------------
template<int CTRL>
__device__ __forceinline__ float dpp_add(float x) {
    int t = __builtin_amdgcn_update_dpp(0, __float_as_int(x), CTRL, 0xf, 0xf, true);
    return x + __int_as_float(t);
}
template<int CTRL>
__device__ __forceinline__ float dpp_max(float x) {
    int xi = __float_as_int(x);
    int t = __builtin_amdgcn_update_dpp(xi, xi, CTRL, 0xf, 0xf, false);
    return fmaxf(x, __int_as_float(t));
}
__device__ __forceinline__ float wave_sum_b(float x) {
    x = dpp_add<0x111>(x); x = dpp_add<0x112>(x);
    x = dpp_add<0x114>(x); x = dpp_add<0x118>(x);
    x = dpp_add<0x142>(x); x = dpp_add<0x143>(x);
    return __int_as_float(__builtin_amdgcn_readlane(__float_as_int(x), 63));
}
__device__ __forceinline__ float wave_max_b(float x) {
    x = dpp_max<0x111>(x); x = dpp_max<0x112>(x);
    x = dpp_max<0x114>(x); x = dpp_max<0x118>(x);
    x = dpp_max<0x142>(x); x = dpp_max<0x143>(x);
    return __int_as_float(__builtin_amdgcn_readlane(__float_as_int(x), 63));
}
__device__ __forceinline__ float row16_sum(float x) {
    x = dpp_add<0x111>(x); x = dpp_add<0x112>(x);
    x = dpp_add<0x114>(x); x = dpp_add<0x118>(x);
    return x;   // lane 15 of each row holds the 16-lane total
}

// ---- prep: repack W into fragment-major bf16, convert rel/ws/fb to f16,
// zero out. MFMA weights stay bf16; gather tables go f16. ----------------
__global__ __launch_bounds__(256) void prep(
        const float* __restrict__ Wc, const float* __restrict__ Wu,
        const float* __restrict__ relf, const float* __restrict__ wsf,
        const float* __restrict__ fbf,
        unsigned short* __restrict__ Wcp, unsigned short* __restrict__ Wup,
        unsigned short* __restrict__ relb, unsigned short* __restrict__ wsh,
        unsigned short* __restrict__ fbh, float* __restrict__ outz,
        int nout, int nrel) {
    int tid = blockIdx.x * 256 + threadIdx.x;
    int nth = gridDim.x * 256;
    for (int i = tid; i < 4 * 2 * 64 * 8; i += nth) {
        int j = i & 7, lane = (i >> 3) & 63, f = i >> 9;
        int ct = f >> 1, kt = f & 1;
        int m = lane & 15, quad = lane >> 4;
        Wcp[i] = f2bfu(Wc[(kt * 32 + quad * 8 + j) * 64 + ct * 16 + m]);
    }
    for (int i = tid; i < 4 * 8 * 64 * 8; i += nth) {
        int j = i & 7, lane = (i >> 3) & 63, f = i >> 9;
        int ct = f >> 3, kt = f & 7;
        int m = lane & 15, quad = lane >> 4;
        Wup[i] = f2bfu(Wu[(kt * 32 + quad * 8 + j) * 64 + ct * 16 + m]);
    }
    for (int i = tid; i < nrel; i += nth) relb[i] = f2hu(relf[i]);
    for (int i = tid; i < 8 * D; i += nth) wsh[i] = f2hu(wsf[i]);
    for (int i = tid; i < D; i += nth) fbh[i] = f2hu(fbf[i]);
    for (int i = tid; i < nout; i += nth) outz[i] = 0.0f;
}

// ---- K=64 projection, pair of row-tiles per wave; packed-W frag init ---
__device__ __forceinline__ void proj64_pair(const float* __restrict__ h,
        const unsigned short* __restrict__ Wp, const float* __restrict__ b,
        unsigned short* __restrict__ out, int rt0) {
    constexpr int K = 64, KT = 2, CTN = 4;
    int lane = threadIdx.x & 63;
    int m = lane & 15, quad = lane >> 4;
    short8 bfr[CTN][KT];
    #pragma unroll
    for (int ct = 0; ct < CTN; ++ct)
        #pragma unroll
        for (int kt = 0; kt < KT; ++kt)
            bfr[ct][kt] = *(const short8*)(Wp + (((ct * 2 + kt) * 64 + lane) << 3));
    float bv[CTN];
    #pragma unroll
    for (int ct = 0; ct < CTN; ++ct) bv[ct] = b[ct * 16 + m];
    int rt1 = rt0 + 1;
    const float* hrow0 = h + (size_t)(rt0 * 16 + m) * K + quad * 8;
    const float* hrow1 = h + (size_t)(rt1 * 16 + m) * K + quad * 8;
    floatx4 a0[KT][2], a1[KT][2];
    #pragma unroll
    for (int kt = 0; kt < KT; ++kt) {
        a0[kt][0] = *(const floatx4*)(hrow0 + kt * 32);
        a0[kt][1] = *(const floatx4*)(hrow0 + kt * 32 + 4);
        a1[kt][0] = *(const floatx4*)(hrow1 + kt * 32);
        a1[kt][1] = *(const floatx4*)(hrow1 + kt * 32 + 4);
    }
    #pragma unroll
    for (int t = 0; t < 2; ++t) {
        floatx4 (*ar)[2] = t ? a1 : a0;
        int rt = t ? rt1 : rt0;
        floatx4 acc[CTN];
        #pragma unroll
        for (int ct = 0; ct < CTN; ++ct) acc[ct] = floatx4{0.f, 0.f, 0.f, 0.f};
        #pragma unroll
        for (int kt = 0; kt < KT; ++kt) {
            short8 af;
            #pragma unroll
            for (int j = 0; j < 4; ++j) {
                af[j]     = (short)f2bfu(ar[kt][0][j]);
                af[j + 4] = (short)f2bfu(ar[kt][1][j]);
            }
            #pragma unroll
            for (int ct = 0; ct < CTN; ++ct)
                acc[ct] = __builtin_amdgcn_mfma_f32_16x16x32_bf16(af, bfr[ct][kt], acc[ct], 0, 0, 0);
        }
        #pragma unroll
        for (int ct = 0; ct < CTN; ++ct) {
            int col = ct * 16 + m;
            #pragma unroll
            for (int reg = 0; reg < 4; ++reg) {
                int row = rt * 16 + quad * 4 + reg;
                out[(size_t)row * 64 + col] = f2hu(fast_tanh(acc[ct][reg] + bv[ct]));
            }
        }
    }
}

// ---- K=256 projection (CTN=2 column-halves); packed-W frag init --------
__device__ __forceinline__ void proj256_body(const float* __restrict__ h,
        const unsigned short* __restrict__ Wp, const float* __restrict__ b,
        unsigned short* __restrict__ out, int ct0, int rt0, int rtstride, int ntiles) {
    constexpr int K = 256, KT = 8, CTN = 2;
    int lane = threadIdx.x & 63;
    int m = lane & 15, quad = lane >> 4;
    short8 bfr[CTN][KT];
    #pragma unroll
    for (int ct = 0; ct < CTN; ++ct)
        #pragma unroll
        for (int kt = 0; kt < KT; ++kt)
            bfr[ct][kt] = *(const short8*)(Wp + ((((ct0 + ct) * 8 + kt) * 64 + lane) << 3));
    float bv[CTN];
    #pragma unroll
    for (int ct = 0; ct < CTN; ++ct) bv[ct] = b[(ct0 + ct) * 16 + m];
    for (int rt = rt0; rt < ntiles; rt += rtstride) {
        floatx4 acc[CTN];
        #pragma unroll
        for (int ct = 0; ct < CTN; ++ct) acc[ct] = floatx4{0.f, 0.f, 0.f, 0.f};
        const float* hrow = h + (size_t)(rt * 16 + m) * K + quad * 8;
        #pragma unroll
        for (int kt = 0; kt < KT; ++kt) {
            floatx4 v0 = *(const floatx4*)(hrow + kt * 32);
            floatx4 v1 = *(const floatx4*)(hrow + kt * 32 + 4);
            short8 af;
            #pragma unroll
            for (int j = 0; j < 4; ++j) {
                af[j]     = (short)f2bfu(v0[j]);
                af[j + 4] = (short)f2bfu(v1[j]);
            }
            #pragma unroll
            for (int ct = 0; ct < CTN; ++ct)
                acc[ct] = __builtin_amdgcn_mfma_f32_16x16x32_bf16(af, bfr[ct][kt], acc[ct], 0, 0, 0);
        }
        #pragma unroll
        for (int ct = 0; ct < CTN; ++ct) {
            int col = (ct0 + ct) * 16 + m;
            #pragma unroll
            for (int reg = 0; reg < 4; ++reg) {
                int row = rt * 16 + quad * 4 + reg;
                out[(size_t)row * 64 + col] = f2hu(fast_tanh(acc[ct][reg] + bv[ct]));
            }
        }
    }
}

// Fused proj: proj256 blocks FIRST (long-running -> start at t=0), then
// proj64. W-frag init is coalesced dwordx4 from prep's packed layout.
__global__ __launch_bounds__(256) void proj_fused(
        const float* __restrict__ hcon, const unsigned short* __restrict__ Wcp,
        const float* __restrict__ bc,
        const float* __restrict__ hun, const unsigned short* __restrict__ Wup,
        const float* __restrict__ bu,
        unsigned short* __restrict__ hc, unsigned short* __restrict__ hu,
        int t64, int t256, int g64, int g256) {
    int bid = blockIdx.x;
    int w = threadIdx.x >> 6;
    if (bid < g256) {
        int wid = bid * 4 + w;
        int half = wid & 1;                 // fixed per wave -> B-frags loaded once
        proj256_body(hun, Wup, bu, hu, half * 2, wid >> 1, g256 * 2, t256);
    } else {
        int wid = (bid - g256) * 4 + w;
        proj64_pair(hcon, Wcp, bc, hc, wid * 2);
    }
}

// Packed-f16 F-layer for ONE edge; each lane owns 4 features (2 __half2).
__device__ __forceinline__ float edge_acc(
        uint2 G0, uint2 G2, uint2 G3, uint2 G4, uint2 F1u,
        const uint2* __restrict__ wku, uint2 fbu, floatx4 owv, __half2 z2) {
    float acc = 0.f;
    #pragma unroll
    for (int p = 0; p < 2; ++p) {
        __half2 F0 = u2h2(p ? G0.y : G0.x);
        __half2 F2 = u2h2(p ? G2.y : G2.x);
        __half2 F3 = u2h2(p ? G3.y : G3.x);
        __half2 F4 = u2h2(p ? G4.y : G4.x);
        __half2 f1 = u2h2(p ? F1u.y : F1u.x);
        __half2 fb2 = u2h2(p ? fbu.y : fbu.x);
        __half2 w0 = u2h2(p ? wku[0].y : wku[0].x);
        __half2 w1 = u2h2(p ? wku[1].y : wku[1].x);
        __half2 w2 = u2h2(p ? wku[2].y : wku[2].x);
        __half2 w3 = u2h2(p ? wku[3].y : wku[3].x);
        __half2 w4 = u2h2(p ? wku[4].y : wku[4].x);
        __half2 w5 = u2h2(p ? wku[5].y : wku[5].x);
        __half2 w6 = u2h2(p ? wku[6].y : wku[6].x);
        __half2 w7 = u2h2(p ? wku[7].y : wku[7].x);
        __half2 t1 = __hfma2(F2, w1, w0);
        __half2 t2 = __hfma2(F2, w5, w4);
        __half2 t3 = __hfma2(F2, w3, w2);
        __half2 t4 = __hfma2(F2, w7, w6);
        __half2 uu = __hfma2(F0, t1, __hmul2(f1, t2));
        __half2 vv = __hfma2(F0, t3, __hmul2(f1, t4));
        __half2 od = __hfma2(F3, uu, __hfma2(F4, vv, fb2));
        __half2 r  = pk_max(od, z2);
        float2 rf  = __half22float2(r);
        acc = fmaf(rf.x, owv[2 * p], fmaf(rf.y, owv[2 * p + 1], acc));
    }
    return acc;
}

// PHASE 1: per-edge logits. 16-lane subgroup per edge, 8 edges/subgroup,
// 128 edges/block -> 3125 blocks / 12500 waves: latency hidden by TLP,
// not compiler-hostile ILP. Iterations fully independent.
__global__ __launch_bounds__(256) void logits_kernel(
        const int* __restrict__ edges, const unsigned short* __restrict__ hc,
        const unsigned short* __restrict__ hu, const unsigned short* __restrict__ relt,
        const unsigned short* __restrict__ wsh, const unsigned short* __restrict__ fbh,
        const float* __restrict__ outw, float* __restrict__ logits, int E) {
    int sub = threadIdx.x & 15;
    int sg  = threadIdx.x >> 4;                 // 0..15 subgroup in block
    int e0  = blockIdx.x * 128 + sg;            // consecutive sg -> consecutive edges

    uint2 wku[8];
    #pragma unroll
    for (int k = 0; k < 8; ++k) wku[k] = *(const uint2*)(wsh + k * D + sub * 4);
    uint2 fbu = *(const uint2*)(fbh + sub * 4);
    floatx4 owv = *(const floatx4*)(outw + sub * 4);
    __half2 z2 = __float2half2_rn(0.f);

    #pragma unroll 2
    for (int k = 0; k < 8; ++k) {
        int e = e0 + k * 16;
        const int* eb = edges + (size_t)e * 8;
        int4 m0 = *(const int4*)eb;             // eg, vi, vj, rel (uniform in subgroup)
        int2 m6 = *(const int2*)(eb + 6);       // e2vi, e2vj
        uint2 G0 = *(const uint2*)(hc   + (size_t)m6.x * D + sub * 4);
        uint2 G2 = *(const uint2*)(relt + (size_t)m0.w * D + sub * 4);
        uint2 G3 = *(const uint2*)(hc   + (size_t)m6.y * D + sub * 4);
        uint2 G4 = *(const uint2*)(hu   + (size_t)m0.z * D + sub * 4);
        uint2 F1 = *(const uint2*)(hu   + (size_t)m0.y * D + sub * 4);
        float acc = edge_acc(G0, G2, G3, G4, F1, wku, fbu, owv, z2);
        float rs = row16_sum(acc);              // lane 15 of row holds total
        if (sub == 15) logits[e] = rs;
    }
}

// PHASE 2: one wave per sorted vi-segment. Coalesced 20-float logit read,
// DPP softmax, atomic scatter at vj. Memory-trivial.
__global__ __launch_bounds__(256) void softmax_scatter(
        const float* __restrict__ natt, const int* __restrict__ edges,
        const float* __restrict__ ey, const float* __restrict__ logits,
        float* __restrict__ out, int N) {
    int lane = threadIdx.x & 63;
    int s = blockIdx.x * 4 + (threadIdx.x >> 6);
    long base = (long)s * KPER;
    const int* eb = edges + base * 8;
    int eg = __builtin_amdgcn_readfirstlane(eb[0]);
    int vi = __builtin_amdgcn_readfirstlane(eb[1]);
    float myl = -INFINITY; int myvj = 0; float eyv = 0.f;
    if (lane < KPER) {
        myl  = logits[base + lane];
        myvj = eb[lane * 8 + 2];
        eyv  = ey[base + lane];
    }
    float na = natt[(size_t)eg * N + vi];
    float mx = wave_max_b(myl);
    float ex = __expf(myl - mx);                // lanes >= 20: exp(-inf) = 0
    float den = wave_sum_b(ex);
    if (lane < KPER) {
        float t = (ex / den) * na * eyv;
        atomicAdd(out + (size_t)eg * N + myvj, t);
    }
}

extern "C" void kernel_launch(void* const* d_in, const int* in_sizes, int n_in,
                              void* d_out, int out_size, void* d_ws, size_t ws_size,
                              hipStream_t stream) {
    const float* natt = (const float*)d_in[0];
    const int*   edges = (const int*)d_in[1];
    const float* ey   = (const float*)d_in[2];
    const float* hun  = (const float*)d_in[3];
    const float* hcon = (const float*)d_in[4];
    const float* Wc   = (const float*)d_in[5];
    const float* bc   = (const float*)d_in[6];
    const float* Wu   = (const float*)d_in[7];
    const float* bu   = (const float*)d_in[8];
    const float* relt = (const float*)d_in[9];
    const float* wsm  = (const float*)d_in[10];
    const float* fb   = (const float*)d_in[11];
    const float* outw = (const float*)d_in[12];
    float* out = (float*)d_out;

    int E    = in_sizes[2];          // 400000 edges
    int S    = E / KPER;             // 20000 sorted vi segments
    int nmem = in_sizes[4] / D;      // 131072 hidden_con rows
    int N    = in_sizes[3] / 256;    // 50000 nodes
    int nrel = in_sizes[9];          // 500*64

    int t64  = nmem / 16;            // 8192 row-tiles
    int t256 = N / 16;               // 3125 row-tiles
    int g64  = t64 / 8;              // 1024 blocks: 4 waves x 2 tiles each
    int g256 = 800;                  // 3200 half-waves, ~2 tiles each

    unsigned short* hc  = (unsigned short*)d_ws;
    unsigned short* hu  = hc + (size_t)nmem * D;
    unsigned short* rb  = hu + (size_t)N * D;
    unsigned short* Wcp = rb + nrel;
    unsigned short* Wup = Wcp + 4096;
    unsigned short* wsh = Wup + 16384;
    unsigned short* fbh = wsh + 8 * D;
    float* logits = (float*)(fbh + D);  // 23.28 MB offset, 4B-aligned

    prep<<<64, 256, 0, stream>>>(Wc, Wu, relt, wsm, fb, Wcp, Wup, rb, wsh, fbh,
                                 out, out_size, nrel);
    proj_fused<<<g256 + g64, 256, 0, stream>>>(hcon, Wcp, bc, hun, Wup, bu,
                                               hc, hu, t64, t256, g64, g256);
    logits_kernel<<<E / 128, 256, 0, stream>>>(edges, hc, hu, rb, wsh, fbh,
                                               outw, logits, E);
    softmax_scatter<<<S / 4, 256, 0, stream>>>(natt, edges, ey, logits, out, N);
}

// Round 4
// 199.296 us; speedup vs baseline: 1.1326x; 1.1326x over previous
//
#include <hip/hip_runtime.h>
#include <hip/hip_bf16.h>
#include <hip/hip_fp16.h>

#define D 64
#define KPER 20

typedef __attribute__((ext_vector_type(8))) short short8;
typedef __attribute__((ext_vector_type(4))) float floatx4;

__device__ __forceinline__ unsigned short f2bfu(float x) {
    __hip_bfloat16 h = __float2bfloat16(x);
    return *reinterpret_cast<unsigned short*>(&h);
}
// f16 bits (tables are f16: 3 more mantissa bits than bf16 AND enables v_pk_* math)
__device__ __forceinline__ unsigned short f2hu(float x) {
    __half h = __float2half(x);
    return *reinterpret_cast<unsigned short*>(&h);
}
union UH2 { unsigned u; __half2 h; };
__device__ __forceinline__ __half2 u2h2(unsigned u) { UH2 x; x.u = u; return x.h; }

// HW packed f32->bf16 convert (RNE): src0 -> bits[15:0], src1 -> bits[31:16]
__device__ __forceinline__ unsigned cvt2bf(float lo, float hi) {
    unsigned r;
    asm("v_cvt_pk_bf16_f32 %0, %1, %2" : "=v"(r) : "v"(lo), "v"(hi));
    return r;
}

// guaranteed-available packed f16 max (avoid header-version-dependent __hmax2)
__device__ __forceinline__ __half2 pk_max(__half2 a, __half2 b) {
    __half2 r;
    asm("v_pk_max_f16 %0, %1, %2" : "=v"(r) : "v"(a), "v"(b));
    return r;
}

__device__ __forceinline__ float fast_tanh(float x) {
    float xc = fminf(fmaxf(x, -15.f), 15.f);
    float e = __expf(2.f * xc);
    return 1.f - 2.f * __builtin_amdgcn_rcpf(1.f + e);
}

// ---- DPP reductions (VALU pipe) ----------------------------------------
template<int CTRL>
__device__ __forceinline__ float dpp_add(float x) {
    int t = __builtin_amdgcn_update_dpp(0, __float_as_int(x), CTRL, 0xf, 0xf, true);
    return x + __int_as_float(t);
}
template<int CTRL>
__device__ __forceinline__ float dpp_max(float x) {
    int xi = __float_as_int(x);
    int t = __builtin_amdgcn_update_dpp(xi, xi, CTRL, 0xf, 0xf, false);
    return fmaxf(x, __int_as_float(t));
}
__device__ __forceinline__ float wave_sum_b(float x) {
    x = dpp_add<0x111>(x); x = dpp_add<0x112>(x);
    x = dpp_add<0x114>(x); x = dpp_add<0x118>(x);
    x = dpp_add<0x142>(x); x = dpp_add<0x143>(x);
    return __int_as_float(__builtin_amdgcn_readlane(__float_as_int(x), 63));
}
__device__ __forceinline__ float wave_max_b(float x) {
    x = dpp_max<0x111>(x); x = dpp_max<0x112>(x);
    x = dpp_max<0x114>(x); x = dpp_max<0x118>(x);
    x = dpp_max<0x142>(x); x = dpp_max<0x143>(x);
    return __int_as_float(__builtin_amdgcn_readlane(__float_as_int(x), 63));
}
__device__ __forceinline__ float row16_sum(float x) {
    x = dpp_add<0x111>(x); x = dpp_add<0x112>(x);
    x = dpp_add<0x114>(x); x = dpp_add<0x118>(x);
    return x;   // lane 15 of each row holds the 16-lane total
}

// ---- prep: repack W into fragment-major bf16, convert rel/ws/fb to f16,
// zero out. MFMA weights stay bf16; gather tables go f16. ----------------
__global__ __launch_bounds__(256) void prep(
        const float* __restrict__ Wc, const float* __restrict__ Wu,
        const float* __restrict__ relf, const float* __restrict__ wsf,
        const float* __restrict__ fbf,
        unsigned short* __restrict__ Wcp, unsigned short* __restrict__ Wup,
        unsigned short* __restrict__ relb, unsigned short* __restrict__ wsh,
        unsigned short* __restrict__ fbh, float* __restrict__ outz,
        int nout, int nrel) {
    int tid = blockIdx.x * 256 + threadIdx.x;
    int nth = gridDim.x * 256;
    for (int i = tid; i < 4 * 2 * 64 * 8; i += nth) {
        int j = i & 7, lane = (i >> 3) & 63, f = i >> 9;
        int ct = f >> 1, kt = f & 1;
        int m = lane & 15, quad = lane >> 4;
        Wcp[i] = f2bfu(Wc[(kt * 32 + quad * 8 + j) * 64 + ct * 16 + m]);
    }
    for (int i = tid; i < 4 * 8 * 64 * 8; i += nth) {
        int j = i & 7, lane = (i >> 3) & 63, f = i >> 9;
        int ct = f >> 3, kt = f & 7;
        int m = lane & 15, quad = lane >> 4;
        Wup[i] = f2bfu(Wu[(kt * 32 + quad * 8 + j) * 64 + ct * 16 + m]);
    }
    for (int i = tid; i < nrel; i += nth) relb[i] = f2hu(relf[i]);
    for (int i = tid; i < 8 * D; i += nth) wsh[i] = f2hu(wsf[i]);
    for (int i = tid; i < D; i += nth) fbh[i] = f2hu(fbf[i]);
    for (int i = tid; i < nout; i += nth) outz[i] = 0.0f;
}

// ---- K=64 projection, pair of row-tiles per wave; packed-W frag init ---
__device__ __forceinline__ void proj64_pair(const float* __restrict__ h,
        const unsigned short* __restrict__ Wp, const float* __restrict__ b,
        unsigned short* __restrict__ out, int rt0) {
    constexpr int K = 64, KT = 2, CTN = 4;
    int lane = threadIdx.x & 63;
    int m = lane & 15, quad = lane >> 4;
    short8 bfr[CTN][KT];
    #pragma unroll
    for (int ct = 0; ct < CTN; ++ct)
        #pragma unroll
        for (int kt = 0; kt < KT; ++kt)
            bfr[ct][kt] = *(const short8*)(Wp + (((ct * 2 + kt) * 64 + lane) << 3));
    float bv[CTN];
    #pragma unroll
    for (int ct = 0; ct < CTN; ++ct) bv[ct] = b[ct * 16 + m];
    int rt1 = rt0 + 1;
    const float* hrow0 = h + (size_t)(rt0 * 16 + m) * K + quad * 8;
    const float* hrow1 = h + (size_t)(rt1 * 16 + m) * K + quad * 8;
    floatx4 a0[KT][2], a1[KT][2];
    #pragma unroll
    for (int kt = 0; kt < KT; ++kt) {
        a0[kt][0] = *(const floatx4*)(hrow0 + kt * 32);
        a0[kt][1] = *(const floatx4*)(hrow0 + kt * 32 + 4);
        a1[kt][0] = *(const floatx4*)(hrow1 + kt * 32);
        a1[kt][1] = *(const floatx4*)(hrow1 + kt * 32 + 4);
    }
    #pragma unroll
    for (int t = 0; t < 2; ++t) {
        floatx4 (*ar)[2] = t ? a1 : a0;
        int rt = t ? rt1 : rt0;
        floatx4 acc[CTN];
        #pragma unroll
        for (int ct = 0; ct < CTN; ++ct) acc[ct] = floatx4{0.f, 0.f, 0.f, 0.f};
        #pragma unroll
        for (int kt = 0; kt < KT; ++kt) {
            union { uint4 u; short8 s; } cc;
            cc.u.x = cvt2bf(ar[kt][0][0], ar[kt][0][1]);
            cc.u.y = cvt2bf(ar[kt][0][2], ar[kt][0][3]);
            cc.u.z = cvt2bf(ar[kt][1][0], ar[kt][1][1]);
            cc.u.w = cvt2bf(ar[kt][1][2], ar[kt][1][3]);
            short8 af = cc.s;
            #pragma unroll
            for (int ct = 0; ct < CTN; ++ct)
                acc[ct] = __builtin_amdgcn_mfma_f32_16x16x32_bf16(af, bfr[ct][kt], acc[ct], 0, 0, 0);
        }
        #pragma unroll
        for (int ct = 0; ct < CTN; ++ct) {
            int col = ct * 16 + m;
            #pragma unroll
            for (int reg = 0; reg < 4; ++reg) {
                int row = rt * 16 + quad * 4 + reg;
                out[(size_t)row * 64 + col] = f2hu(fast_tanh(acc[ct][reg] + bv[ct]));
            }
        }
    }
}

// ---- K=256 projection (CTN=2 column-halves); packed-W frag init --------
__device__ __forceinline__ void proj256_body(const float* __restrict__ h,
        const unsigned short* __restrict__ Wp, const float* __restrict__ b,
        unsigned short* __restrict__ out, int ct0, int rt0, int rtstride, int ntiles) {
    constexpr int K = 256, KT = 8, CTN = 2;
    int lane = threadIdx.x & 63;
    int m = lane & 15, quad = lane >> 4;
    short8 bfr[CTN][KT];
    #pragma unroll
    for (int ct = 0; ct < CTN; ++ct)
        #pragma unroll
        for (int kt = 0; kt < KT; ++kt)
            bfr[ct][kt] = *(const short8*)(Wp + ((((ct0 + ct) * 8 + kt) * 64 + lane) << 3));
    float bv[CTN];
    #pragma unroll
    for (int ct = 0; ct < CTN; ++ct) bv[ct] = b[(ct0 + ct) * 16 + m];
    for (int rt = rt0; rt < ntiles; rt += rtstride) {
        floatx4 acc[CTN];
        #pragma unroll
        for (int ct = 0; ct < CTN; ++ct) acc[ct] = floatx4{0.f, 0.f, 0.f, 0.f};
        const float* hrow = h + (size_t)(rt * 16 + m) * K + quad * 8;
        #pragma unroll
        for (int kt = 0; kt < KT; ++kt) {
            floatx4 v0 = *(const floatx4*)(hrow + kt * 32);
            floatx4 v1 = *(const floatx4*)(hrow + kt * 32 + 4);
            union { uint4 u; short8 s; } cc;
            cc.u.x = cvt2bf(v0[0], v0[1]);
            cc.u.y = cvt2bf(v0[2], v0[3]);
            cc.u.z = cvt2bf(v1[0], v1[1]);
            cc.u.w = cvt2bf(v1[2], v1[3]);
            short8 af = cc.s;
            #pragma unroll
            for (int ct = 0; ct < CTN; ++ct)
                acc[ct] = __builtin_amdgcn_mfma_f32_16x16x32_bf16(af, bfr[ct][kt], acc[ct], 0, 0, 0);
        }
        #pragma unroll
        for (int ct = 0; ct < CTN; ++ct) {
            int col = (ct0 + ct) * 16 + m;
            #pragma unroll
            for (int reg = 0; reg < 4; ++reg) {
                int row = rt * 16 + quad * 4 + reg;
                out[(size_t)row * 64 + col] = f2hu(fast_tanh(acc[ct][reg] + bv[ct]));
            }
        }
    }
}

// Fused proj: proj256 blocks FIRST (long-running -> start at t=0), then
// proj64. W-frag init is coalesced dwordx4 from prep's packed layout.
__global__ __launch_bounds__(256) void proj_fused(
        const float* __restrict__ hcon, const unsigned short* __restrict__ Wcp,
        const float* __restrict__ bc,
        const float* __restrict__ hun, const unsigned short* __restrict__ Wup,
        const float* __restrict__ bu,
        unsigned short* __restrict__ hc, unsigned short* __restrict__ hu,
        int t64, int t256, int g64, int g256) {
    int bid = blockIdx.x;
    int w = threadIdx.x >> 6;
    if (bid < g256) {
        int wid = bid * 4 + w;
        int half = wid & 1;                 // fixed per wave -> B-frags loaded once
        proj256_body(hun, Wup, bu, hu, half * 2, wid >> 1, g256 * 2, t256);
    } else {
        int wid = (bid - g256) * 4 + w;
        proj64_pair(hcon, Wcp, bc, hc, wid * 2);
    }
}

// Packed-f16 F-layer for ONE edge; each lane owns 4 features (2 __half2).
__device__ __forceinline__ float edge_acc(
        uint2 G0, uint2 G2, uint2 G3, uint2 G4, uint2 F1u,
        const uint2* __restrict__ wku, uint2 fbu, floatx4 owv, __half2 z2) {
    float acc = 0.f;
    #pragma unroll
    for (int p = 0; p < 2; ++p) {
        __half2 F0 = u2h2(p ? G0.y : G0.x);
        __half2 F2 = u2h2(p ? G2.y : G2.x);
        __half2 F3 = u2h2(p ? G3.y : G3.x);
        __half2 F4 = u2h2(p ? G4.y : G4.x);
        __half2 f1 = u2h2(p ? F1u.y : F1u.x);
        __half2 fb2 = u2h2(p ? fbu.y : fbu.x);
        __half2 w0 = u2h2(p ? wku[0].y : wku[0].x);
        __half2 w1 = u2h2(p ? wku[1].y : wku[1].x);
        __half2 w2 = u2h2(p ? wku[2].y : wku[2].x);
        __half2 w3 = u2h2(p ? wku[3].y : wku[3].x);
        __half2 w4 = u2h2(p ? wku[4].y : wku[4].x);
        __half2 w5 = u2h2(p ? wku[5].y : wku[5].x);
        __half2 w6 = u2h2(p ? wku[6].y : wku[6].x);
        __half2 w7 = u2h2(p ? wku[7].y : wku[7].x);
        __half2 t1 = __hfma2(F2, w1, w0);
        __half2 t2 = __hfma2(F2, w5, w4);
        __half2 t3 = __hfma2(F2, w3, w2);
        __half2 t4 = __hfma2(F2, w7, w6);
        __half2 uu = __hfma2(F0, t1, __hmul2(f1, t2));
        __half2 vv = __hfma2(F0, t3, __hmul2(f1, t4));
        __half2 od = __hfma2(F3, uu, __hfma2(F4, vv, fb2));
        __half2 r  = pk_max(od, z2);
        float2 rf  = __half22float2(r);
        acc = fmaf(rf.x, owv[2 * p], fmaf(rf.y, owv[2 * p + 1], acc));
    }
    return acc;
}

// TWO sorted vi-segments per wave, flattened into a 10-step loop with a
// FORCED 1-deep prefetch pipeline: step t+1's 4 row-gathers are issued
// before step t's compute, pinned by sched_barrier(0) so the compiler
// cannot re-sink them (R2 evidence: VGPR=60 proved it serialized the
// up-front gathers). Compute then waits at vmcnt(4), not vmcnt(0).
__global__ __launch_bounds__(256) void edge_kernel(
        const float* __restrict__ natt, const int* __restrict__ edges,
        const float* __restrict__ ey, const unsigned short* __restrict__ hc,
        const unsigned short* __restrict__ hu, const unsigned short* __restrict__ relt,
        const unsigned short* __restrict__ wsh, const unsigned short* __restrict__ fbh,
        const float* __restrict__ outw, float* __restrict__ out, int N) {
    int lane = threadIdx.x & 63;
    int g = lane >> 4, sub = lane & 15;
    int l2 = lane >> 2;
    int wid = blockIdx.x * 4 + (threadIdx.x >> 6);
    long baseA = (long)(wid * 2) * KPER;
    long baseB = baseA + KPER;
    const int* ebA = edges + baseA * 8;
    const int* ebB = edges + baseB * 8;

    // ---- metadata (both segments), 8B vector loads -----------------------
    int2 h0A = *(const int2*)ebA;                 // (eg, vi)
    int2 h0B = *(const int2*)ebB;
    const int* egpA = ebA + g * 8;
    const int* egpB = ebB + g * 8;
    int2 m23A[5], m67A[5], m23B[5], m67B[5];      // (vj,rel), (e2vi,e2vj)
    #pragma unroll
    for (int i = 0; i < 5; ++i) {
        m23A[i] = *(const int2*)(egpA + i * 32 + 2);
        m67A[i] = *(const int2*)(egpA + i * 32 + 6);
        m23B[i] = *(const int2*)(egpB + i * 32 + 2);
        m67B[i] = *(const int2*)(egpB + i * 32 + 6);
    }
    // atomic-tail operands, off the critical path
    int myvjA = 0, myvjB = 0; float eyA = 0.f, eyB = 0.f;
    if (lane < KPER) {
        myvjA = ebA[lane * 8 + 2];
        myvjB = ebB[lane * 8 + 2];
        eyA = ey[baseA + lane];
        eyB = ey[baseB + lane];
    }
    int egA = __builtin_amdgcn_readfirstlane(h0A.x);
    int viA = __builtin_amdgcn_readfirstlane(h0A.y);
    int egB = __builtin_amdgcn_readfirstlane(h0B.x);
    int viB = __builtin_amdgcn_readfirstlane(h0B.y);
    uint2 F1A = *(const uint2*)(hu + (size_t)viA * D + sub * 4);
    uint2 F1B = *(const uint2*)(hu + (size_t)viB * D + sub * 4);
    float naA = natt[(size_t)egA * N + viA];
    float naB = natt[(size_t)egB * N + viB];

    // ---- per-lane constants (f16 ws/fb; f32 out_w) -----------------------
    uint2 wku[8];
    #pragma unroll
    for (int k = 0; k < 8; ++k) wku[k] = *(const uint2*)(wsh + k * D + sub * 4);
    uint2 fbu = *(const uint2*)(fbh + sub * 4);
    floatx4 owv = *(const floatx4*)(outw + sub * 4);
    __half2 z2 = __float2half2_rn(0.f);

    // ---- pipelined 10-step gather/compute loop ---------------------------
    float mylA = -INFINITY, mylB = -INFINITY;
    uint2 c0 = *(const uint2*)(hc   + (size_t)m67A[0].x * D + sub * 4);
    uint2 c2 = *(const uint2*)(relt + (size_t)m23A[0].y * D + sub * 4);
    uint2 c3 = *(const uint2*)(hc   + (size_t)m67A[0].y * D + sub * 4);
    uint2 c4 = *(const uint2*)(hu   + (size_t)m23A[0].x * D + sub * 4);
    #pragma unroll
    for (int t = 0; t < 10; ++t) {
        uint2 n0 = c0, n2 = c2, n3 = c3, n4 = c4;
        if (t < 9) {
            const int tn = t + 1;
            const int2* p23 = (tn < 5) ? m23A : m23B;
            const int2* p67 = (tn < 5) ? m67A : m67B;
            const int ii = (tn < 5) ? tn : tn - 5;
            n0 = *(const uint2*)(hc   + (size_t)p67[ii].x * D + sub * 4);
            n2 = *(const uint2*)(relt + (size_t)p23[ii].y * D + sub * 4);
            n3 = *(const uint2*)(hc   + (size_t)p67[ii].y * D + sub * 4);
            n4 = *(const uint2*)(hu   + (size_t)p23[ii].x * D + sub * 4);
        }
        __builtin_amdgcn_sched_barrier(0);   // pin: next-step loads issue first
        uint2 F1 = (t < 5) ? F1A : F1B;
        float acc = edge_acc(c0, c2, c3, c4, F1, wku, fbu, owv, z2);
        float rs = row16_sum(acc);
        float tot = __shfl(rs, ((lane & 3) << 4) + 15);
        if (t < 5) mylA = (l2 == t) ? tot : mylA;
        else       mylB = (l2 == (t - 5)) ? tot : mylB;
        c0 = n0; c2 = n2; c3 = n3; c4 = n4;
    }

    // ---- segment A: softmax + scatter ------------------------------------
    float mxA = wave_max_b(mylA);
    float exA = __expf(mylA - mxA);
    float denA = wave_sum_b(exA);
    if (lane < KPER) {
        float t = (exA / denA) * naA * eyA;
        atomicAdd(out + (size_t)egA * N + myvjA, t);
    }
    // ---- segment B -------------------------------------------------------
    float mxB = wave_max_b(mylB);
    float exB = __expf(mylB - mxB);
    float denB = wave_sum_b(exB);
    if (lane < KPER) {
        float t = (exB / denB) * naB * eyB;
        atomicAdd(out + (size_t)egB * N + myvjB, t);
    }
}

extern "C" void kernel_launch(void* const* d_in, const int* in_sizes, int n_in,
                              void* d_out, int out_size, void* d_ws, size_t ws_size,
                              hipStream_t stream) {
    const float* natt = (const float*)d_in[0];
    const int*   edges = (const int*)d_in[1];
    const float* ey   = (const float*)d_in[2];
    const float* hun  = (const float*)d_in[3];
    const float* hcon = (const float*)d_in[4];
    const float* Wc   = (const float*)d_in[5];
    const float* bc   = (const float*)d_in[6];
    const float* Wu   = (const float*)d_in[7];
    const float* bu   = (const float*)d_in[8];
    const float* relt = (const float*)d_in[9];
    const float* wsm  = (const float*)d_in[10];
    const float* fb   = (const float*)d_in[11];
    const float* outw = (const float*)d_in[12];
    float* out = (float*)d_out;

    int E    = in_sizes[2];          // 400000 edges
    int S    = E / KPER;             // 20000 sorted vi segments
    int nmem = in_sizes[4] / D;      // 131072 hidden_con rows
    int N    = in_sizes[3] / 256;    // 50000 nodes
    int nrel = in_sizes[9];          // 500*64

    int t64  = nmem / 16;            // 8192 row-tiles
    int t256 = N / 16;               // 3125 row-tiles
    int g64  = t64 / 8;              // 1024 blocks: 4 waves x 2 tiles each
    int g256 = 800;                  // 3200 half-waves, ~2 tiles each

    unsigned short* hc  = (unsigned short*)d_ws;
    unsigned short* hu  = hc + (size_t)nmem * D;
    unsigned short* rb  = hu + (size_t)N * D;
    unsigned short* Wcp = rb + nrel;
    unsigned short* Wup = Wcp + 4096;
    unsigned short* wsh = Wup + 16384;
    unsigned short* fbh = wsh + 8 * D;

    prep<<<64, 256, 0, stream>>>(Wc, Wu, relt, wsm, fb, Wcp, Wup, rb, wsh, fbh,
                                 out, out_size, nrel);
    proj_fused<<<g256 + g64, 256, 0, stream>>>(hcon, Wcp, bc, hun, Wup, bu,
                                               hc, hu, t64, t256, g64, g256);
    edge_kernel<<<S / 8, 256, 0, stream>>>(natt, edges, ey, hc, hu, rb,
                                           wsh, fbh, outw, out, N);
}

// Round 5
// 196.380 us; speedup vs baseline: 1.1494x; 1.0148x over previous
//
#include <hip/hip_runtime.h>
#include <hip/hip_bf16.h>
#include <hip/hip_fp16.h>

#define D 64
#define KPER 20

typedef __attribute__((ext_vector_type(8))) short short8;
typedef __attribute__((ext_vector_type(4))) float floatx4;

__device__ __forceinline__ unsigned short f2bfu(float x) {
    __hip_bfloat16 h = __float2bfloat16(x);
    return *reinterpret_cast<unsigned short*>(&h);
}
// f16 bits (tables are f16: 3 more mantissa bits than bf16 AND enables v_pk_* math)
__device__ __forceinline__ unsigned short f2hu(float x) {
    __half h = __float2half(x);
    return *reinterpret_cast<unsigned short*>(&h);
}
union UH2 { unsigned u; __half2 h; };
__device__ __forceinline__ __half2 u2h2(unsigned u) { UH2 x; x.u = u; return x.h; }

// HW packed f32->bf16 convert (RNE): src0 -> bits[15:0], src1 -> bits[31:16]
__device__ __forceinline__ unsigned cvt2bf(float lo, float hi) {
    unsigned r;
    asm("v_cvt_pk_bf16_f32 %0, %1, %2" : "=v"(r) : "v"(lo), "v"(hi));
    return r;
}

// guaranteed-available packed f16 max (avoid header-version-dependent __hmax2)
__device__ __forceinline__ __half2 pk_max(__half2 a, __half2 b) {
    __half2 r;
    asm("v_pk_max_f16 %0, %1, %2" : "=v"(r) : "v"(a), "v"(b));
    return r;
}

__device__ __forceinline__ float fast_tanh(float x) {
    float xc = fminf(fmaxf(x, -15.f), 15.f);
    float e = __expf(2.f * xc);
    return 1.f - 2.f * __builtin_amdgcn_rcpf(1.f + e);
}

// ---- DPP reductions (VALU pipe) ----------------------------------------
template<int CTRL>
__device__ __forceinline__ float dpp_add(float x) {
    int t = __builtin_amdgcn_update_dpp(0, __float_as_int(x), CTRL, 0xf, 0xf, true);
    return x + __int_as_float(t);
}
template<int CTRL>
__device__ __forceinline__ float dpp_max(float x) {
    int xi = __float_as_int(x);
    int t = __builtin_amdgcn_update_dpp(xi, xi, CTRL, 0xf, 0xf, false);
    return fmaxf(x, __int_as_float(t));
}
__device__ __forceinline__ float wave_sum_b(float x) {
    x = dpp_add<0x111>(x); x = dpp_add<0x112>(x);
    x = dpp_add<0x114>(x); x = dpp_add<0x118>(x);
    x = dpp_add<0x142>(x); x = dpp_add<0x143>(x);
    return __int_as_float(__builtin_amdgcn_readlane(__float_as_int(x), 63));
}
__device__ __forceinline__ float wave_max_b(float x) {
    x = dpp_max<0x111>(x); x = dpp_max<0x112>(x);
    x = dpp_max<0x114>(x); x = dpp_max<0x118>(x);
    x = dpp_max<0x142>(x); x = dpp_max<0x143>(x);
    return __int_as_float(__builtin_amdgcn_readlane(__float_as_int(x), 63));
}
__device__ __forceinline__ float row16_sum(float x) {
    x = dpp_add<0x111>(x); x = dpp_add<0x112>(x);
    x = dpp_add<0x114>(x); x = dpp_add<0x118>(x);
    return x;   // lane 15 of each row holds the 16-lane total
}

// ---- prep: repack W into fragment-major bf16, convert rel/ws/fb to f16,
// zero out. MFMA weights stay bf16; gather tables go f16. ----------------
__global__ __launch_bounds__(256) void prep(
        const float* __restrict__ Wc, const float* __restrict__ Wu,
        const float* __restrict__ relf, const float* __restrict__ wsf,
        const float* __restrict__ fbf,
        unsigned short* __restrict__ Wcp, unsigned short* __restrict__ Wup,
        unsigned short* __restrict__ relb, unsigned short* __restrict__ wsh,
        unsigned short* __restrict__ fbh, float* __restrict__ outz,
        int nout, int nrel) {
    int tid = blockIdx.x * 256 + threadIdx.x;
    int nth = gridDim.x * 256;
    for (int i = tid; i < 4 * 2 * 64 * 8; i += nth) {
        int j = i & 7, lane = (i >> 3) & 63, f = i >> 9;
        int ct = f >> 1, kt = f & 1;
        int m = lane & 15, quad = lane >> 4;
        Wcp[i] = f2bfu(Wc[(kt * 32 + quad * 8 + j) * 64 + ct * 16 + m]);
    }
    for (int i = tid; i < 4 * 8 * 64 * 8; i += nth) {
        int j = i & 7, lane = (i >> 3) & 63, f = i >> 9;
        int ct = f >> 3, kt = f & 7;
        int m = lane & 15, quad = lane >> 4;
        Wup[i] = f2bfu(Wu[(kt * 32 + quad * 8 + j) * 64 + ct * 16 + m]);
    }
    for (int i = tid; i < nrel; i += nth) relb[i] = f2hu(relf[i]);
    for (int i = tid; i < 8 * D; i += nth) wsh[i] = f2hu(wsf[i]);
    for (int i = tid; i < D; i += nth) fbh[i] = f2hu(fbf[i]);
    for (int i = tid; i < nout; i += nth) outz[i] = 0.0f;
}

// ---- K=64 projection, pair of row-tiles per wave; packed-W frag init ---
__device__ __forceinline__ void proj64_pair(const float* __restrict__ h,
        const unsigned short* __restrict__ Wp, const float* __restrict__ b,
        unsigned short* __restrict__ out, int rt0) {
    constexpr int K = 64, KT = 2, CTN = 4;
    int lane = threadIdx.x & 63;
    int m = lane & 15, quad = lane >> 4;
    short8 bfr[CTN][KT];
    #pragma unroll
    for (int ct = 0; ct < CTN; ++ct)
        #pragma unroll
        for (int kt = 0; kt < KT; ++kt)
            bfr[ct][kt] = *(const short8*)(Wp + (((ct * 2 + kt) * 64 + lane) << 3));
    float bv[CTN];
    #pragma unroll
    for (int ct = 0; ct < CTN; ++ct) bv[ct] = b[ct * 16 + m];
    int rt1 = rt0 + 1;
    const float* hrow0 = h + (size_t)(rt0 * 16 + m) * K + quad * 8;
    const float* hrow1 = h + (size_t)(rt1 * 16 + m) * K + quad * 8;
    floatx4 a0[KT][2], a1[KT][2];
    #pragma unroll
    for (int kt = 0; kt < KT; ++kt) {
        a0[kt][0] = *(const floatx4*)(hrow0 + kt * 32);
        a0[kt][1] = *(const floatx4*)(hrow0 + kt * 32 + 4);
        a1[kt][0] = *(const floatx4*)(hrow1 + kt * 32);
        a1[kt][1] = *(const floatx4*)(hrow1 + kt * 32 + 4);
    }
    #pragma unroll
    for (int t = 0; t < 2; ++t) {
        floatx4 (*ar)[2] = t ? a1 : a0;
        int rt = t ? rt1 : rt0;
        floatx4 acc[CTN];
        #pragma unroll
        for (int ct = 0; ct < CTN; ++ct) acc[ct] = floatx4{0.f, 0.f, 0.f, 0.f};
        #pragma unroll
        for (int kt = 0; kt < KT; ++kt) {
            union { uint4 u; short8 s; } cc;
            cc.u.x = cvt2bf(ar[kt][0][0], ar[kt][0][1]);
            cc.u.y = cvt2bf(ar[kt][0][2], ar[kt][0][3]);
            cc.u.z = cvt2bf(ar[kt][1][0], ar[kt][1][1]);
            cc.u.w = cvt2bf(ar[kt][1][2], ar[kt][1][3]);
            short8 af = cc.s;
            #pragma unroll
            for (int ct = 0; ct < CTN; ++ct)
                acc[ct] = __builtin_amdgcn_mfma_f32_16x16x32_bf16(af, bfr[ct][kt], acc[ct], 0, 0, 0);
        }
        #pragma unroll
        for (int ct = 0; ct < CTN; ++ct) {
            int col = ct * 16 + m;
            #pragma unroll
            for (int reg = 0; reg < 4; ++reg) {
                int row = rt * 16 + quad * 4 + reg;
                out[(size_t)row * 64 + col] = f2hu(fast_tanh(acc[ct][reg] + bv[ct]));
            }
        }
    }
}

// ---- K=256 projection (CTN=2 column-halves); packed-W frag init --------
__device__ __forceinline__ void proj256_body(const float* __restrict__ h,
        const unsigned short* __restrict__ Wp, const float* __restrict__ b,
        unsigned short* __restrict__ out, int ct0, int rt0, int rtstride, int ntiles) {
    constexpr int K = 256, KT = 8, CTN = 2;
    int lane = threadIdx.x & 63;
    int m = lane & 15, quad = lane >> 4;
    short8 bfr[CTN][KT];
    #pragma unroll
    for (int ct = 0; ct < CTN; ++ct)
        #pragma unroll
        for (int kt = 0; kt < KT; ++kt)
            bfr[ct][kt] = *(const short8*)(Wp + ((((ct0 + ct) * 8 + kt) * 64 + lane) << 3));
    float bv[CTN];
    #pragma unroll
    for (int ct = 0; ct < CTN; ++ct) bv[ct] = b[(ct0 + ct) * 16 + m];
    for (int rt = rt0; rt < ntiles; rt += rtstride) {
        floatx4 acc[CTN];
        #pragma unroll
        for (int ct = 0; ct < CTN; ++ct) acc[ct] = floatx4{0.f, 0.f, 0.f, 0.f};
        const float* hrow = h + (size_t)(rt * 16 + m) * K + quad * 8;
        #pragma unroll
        for (int kt = 0; kt < KT; ++kt) {
            floatx4 v0 = *(const floatx4*)(hrow + kt * 32);
            floatx4 v1 = *(const floatx4*)(hrow + kt * 32 + 4);
            union { uint4 u; short8 s; } cc;
            cc.u.x = cvt2bf(v0[0], v0[1]);
            cc.u.y = cvt2bf(v0[2], v0[3]);
            cc.u.z = cvt2bf(v1[0], v1[1]);
            cc.u.w = cvt2bf(v1[2], v1[3]);
            short8 af = cc.s;
            #pragma unroll
            for (int ct = 0; ct < CTN; ++ct)
                acc[ct] = __builtin_amdgcn_mfma_f32_16x16x32_bf16(af, bfr[ct][kt], acc[ct], 0, 0, 0);
        }
        #pragma unroll
        for (int ct = 0; ct < CTN; ++ct) {
            int col = (ct0 + ct) * 16 + m;
            #pragma unroll
            for (int reg = 0; reg < 4; ++reg) {
                int row = rt * 16 + quad * 4 + reg;
                out[(size_t)row * 64 + col] = f2hu(fast_tanh(acc[ct][reg] + bv[ct]));
            }
        }
    }
}

// Fused proj: proj256 blocks FIRST (long-running -> start at t=0), then
// proj64. W-frag init is coalesced dwordx4 from prep's packed layout.
__global__ __launch_bounds__(256) void proj_fused(
        const float* __restrict__ hcon, const unsigned short* __restrict__ Wcp,
        const float* __restrict__ bc,
        const float* __restrict__ hun, const unsigned short* __restrict__ Wup,
        const float* __restrict__ bu,
        unsigned short* __restrict__ hc, unsigned short* __restrict__ hu,
        int t64, int t256, int g64, int g256) {
    int bid = blockIdx.x;
    int w = threadIdx.x >> 6;
    if (bid < g256) {
        int wid = bid * 4 + w;
        int half = wid & 1;                 // fixed per wave -> B-frags loaded once
        proj256_body(hun, Wup, bu, hu, half * 2, wid >> 1, g256 * 2, t256);
    } else {
        int wid = (bid - g256) * 4 + w;
        proj64_pair(hcon, Wcp, bc, hc, wid * 2);
    }
}

// Packed-f16 F-layer for one segment. Tables are f16, so the gathered
// uint2 IS two __half2 values -> zero unpack, v_pk_* math.
__device__ __forceinline__ float seg_myl(
        const uint2* __restrict__ G0, const uint2* __restrict__ G2,
        const uint2* __restrict__ G3, const uint2* __restrict__ G4,
        uint2 F1u, const uint2* __restrict__ wku, uint2 fbu, floatx4 owv,
        int lane, int l2, __half2 z2) {
    __half2 f1[2]  = { u2h2(F1u.x), u2h2(F1u.y) };
    __half2 fb2[2] = { u2h2(fbu.x), u2h2(fbu.y) };
    float myl = -INFINITY;
    #pragma unroll
    for (int i = 0; i < 5; ++i) {
        float acc = 0.f;
        #pragma unroll
        for (int p = 0; p < 2; ++p) {
            __half2 F0 = u2h2(p ? G0[i].y : G0[i].x);
            __half2 F2 = u2h2(p ? G2[i].y : G2[i].x);
            __half2 F3 = u2h2(p ? G3[i].y : G3[i].x);
            __half2 F4 = u2h2(p ? G4[i].y : G4[i].x);
            __half2 w0 = u2h2(p ? wku[0].y : wku[0].x);
            __half2 w1 = u2h2(p ? wku[1].y : wku[1].x);
            __half2 w2 = u2h2(p ? wku[2].y : wku[2].x);
            __half2 w3 = u2h2(p ? wku[3].y : wku[3].x);
            __half2 w4 = u2h2(p ? wku[4].y : wku[4].x);
            __half2 w5 = u2h2(p ? wku[5].y : wku[5].x);
            __half2 w6 = u2h2(p ? wku[6].y : wku[6].x);
            __half2 w7 = u2h2(p ? wku[7].y : wku[7].x);
            __half2 t1 = __hfma2(F2, w1, w0);
            __half2 t2 = __hfma2(F2, w5, w4);
            __half2 t3 = __hfma2(F2, w3, w2);
            __half2 t4 = __hfma2(F2, w7, w6);
            __half2 uu = __hfma2(F0, t1, __hmul2(f1[p], t2));
            __half2 vv = __hfma2(F0, t3, __hmul2(f1[p], t4));
            __half2 od = __hfma2(F3, uu, __hfma2(F4, vv, fb2[p]));
            __half2 r  = pk_max(od, z2);
            float2 rf  = __half22float2(r);
            acc = fmaf(rf.x, owv[2 * p], fmaf(rf.y, owv[2 * p + 1], acc));
        }
        float rs = row16_sum(acc);
        float tot = __shfl(rs, ((lane & 3) << 4) + 15);
        myl = (l2 == i) ? tot : myl;
    }
    return myl;
}

// TWO sorted vi-segments per wave, ALL 42 feature gathers issued up-front.
// __launch_bounds__(256,3) raises the VGPR budget to ~170 so the compiler
// KEEPS them in flight (R2 evidence: default bounds -> VGPR 60 -> gathers
// re-sunk into serial clusters; measured occupancy is only ~2.5 waves/SIMD
// anyway, so trading the 8-wave cap for ~40 outstanding loads is net win).
__global__ __launch_bounds__(256, 3) void edge_kernel(
        const float* __restrict__ natt, const int* __restrict__ edges,
        const float* __restrict__ ey, const unsigned short* __restrict__ hc,
        const unsigned short* __restrict__ hu, const unsigned short* __restrict__ relt,
        const unsigned short* __restrict__ wsh, const unsigned short* __restrict__ fbh,
        const float* __restrict__ outw, float* __restrict__ out, int N) {
    int lane = threadIdx.x & 63;
    int g = lane >> 4, sub = lane & 15;
    int l2 = lane >> 2;
    int wid = blockIdx.x * 4 + (threadIdx.x >> 6);
    long baseA = (long)(wid * 2) * KPER;
    long baseB = baseA + KPER;
    const int* ebA = edges + baseA * 8;
    const int* ebB = edges + baseB * 8;

    // ---- metadata (both segments), 8B vector loads -----------------------
    int2 h0A = *(const int2*)ebA;                 // (eg, vi)
    int2 h0B = *(const int2*)ebB;
    const int* egpA = ebA + g * 8;
    const int* egpB = ebB + g * 8;
    int2 m23A[5], m67A[5], m23B[5], m67B[5];      // (vj,rel), (e2vi,e2vj)
    #pragma unroll
    for (int i = 0; i < 5; ++i) {
        m23A[i] = *(const int2*)(egpA + i * 32 + 2);
        m67A[i] = *(const int2*)(egpA + i * 32 + 6);
        m23B[i] = *(const int2*)(egpB + i * 32 + 2);
        m67B[i] = *(const int2*)(egpB + i * 32 + 6);
    }
    // atomic-tail operands, off the critical path
    int myvjA = 0, myvjB = 0; float eyA = 0.f, eyB = 0.f;
    if (lane < KPER) {
        myvjA = ebA[lane * 8 + 2];
        myvjB = ebB[lane * 8 + 2];
        eyA = ey[baseA + lane];
        eyB = ey[baseB + lane];
    }
    int egA = __builtin_amdgcn_readfirstlane(h0A.x);
    int viA = __builtin_amdgcn_readfirstlane(h0A.y);
    int egB = __builtin_amdgcn_readfirstlane(h0B.x);
    int viB = __builtin_amdgcn_readfirstlane(h0B.y);

    // ---- all 42 f16-row gathers (A first, then B) ------------------------
    uint2 GA0[5], GA2[5], GA3[5], GA4[5];
    #pragma unroll
    for (int i = 0; i < 5; ++i) {
        GA0[i] = *(const uint2*)(hc   + (size_t)m67A[i].x * D + sub * 4);
        GA2[i] = *(const uint2*)(relt + (size_t)m23A[i].y * D + sub * 4);
        GA3[i] = *(const uint2*)(hc   + (size_t)m67A[i].y * D + sub * 4);
        GA4[i] = *(const uint2*)(hu   + (size_t)m23A[i].x * D + sub * 4);
    }
    uint2 F1A = *(const uint2*)(hu + (size_t)viA * D + sub * 4);
    uint2 GB0[5], GB2[5], GB3[5], GB4[5];
    #pragma unroll
    for (int i = 0; i < 5; ++i) {
        GB0[i] = *(const uint2*)(hc   + (size_t)m67B[i].x * D + sub * 4);
        GB2[i] = *(const uint2*)(relt + (size_t)m23B[i].y * D + sub * 4);
        GB3[i] = *(const uint2*)(hc   + (size_t)m67B[i].y * D + sub * 4);
        GB4[i] = *(const uint2*)(hu   + (size_t)m23B[i].x * D + sub * 4);
    }
    uint2 F1B = *(const uint2*)(hu + (size_t)viB * D + sub * 4);
    float naA = natt[(size_t)egA * N + viA];
    float naB = natt[(size_t)egB * N + viB];

    // ---- per-lane constants (f16 ws/fb; f32 out_w) -----------------------
    uint2 wku[8];
    #pragma unroll
    for (int k = 0; k < 8; ++k) wku[k] = *(const uint2*)(wsh + k * D + sub * 4);
    uint2 fbu = *(const uint2*)(fbh + sub * 4);
    floatx4 owv = *(const floatx4*)(outw + sub * 4);
    __half2 z2 = __float2half2_rn(0.f);

    // ---- segment A: F-layer + softmax + scatter --------------------------
    float mylA = seg_myl(GA0, GA2, GA3, GA4, F1A, wku, fbu, owv, lane, l2, z2);
    float mxA = wave_max_b(mylA);
    float exA = __expf(mylA - mxA);
    float denA = wave_sum_b(exA);
    if (lane < KPER) {
        float t = (exA / denA) * naA * eyA;
        atomicAdd(out + (size_t)egA * N + myvjA, t);
    }
    // ---- segment B -------------------------------------------------------
    float mylB = seg_myl(GB0, GB2, GB3, GB4, F1B, wku, fbu, owv, lane, l2, z2);
    float mxB = wave_max_b(mylB);
    float exB = __expf(mylB - mxB);
    float denB = wave_sum_b(exB);
    if (lane < KPER) {
        float t = (exB / denB) * naB * eyB;
        atomicAdd(out + (size_t)egB * N + myvjB, t);
    }
}

extern "C" void kernel_launch(void* const* d_in, const int* in_sizes, int n_in,
                              void* d_out, int out_size, void* d_ws, size_t ws_size,
                              hipStream_t stream) {
    const float* natt = (const float*)d_in[0];
    const int*   edges = (const int*)d_in[1];
    const float* ey   = (const float*)d_in[2];
    const float* hun  = (const float*)d_in[3];
    const float* hcon = (const float*)d_in[4];
    const float* Wc   = (const float*)d_in[5];
    const float* bc   = (const float*)d_in[6];
    const float* Wu   = (const float*)d_in[7];
    const float* bu   = (const float*)d_in[8];
    const float* relt = (const float*)d_in[9];
    const float* wsm  = (const float*)d_in[10];
    const float* fb   = (const float*)d_in[11];
    const float* outw = (const float*)d_in[12];
    float* out = (float*)d_out;

    int E    = in_sizes[2];          // 400000 edges
    int S    = E / KPER;             // 20000 sorted vi segments
    int nmem = in_sizes[4] / D;      // 131072 hidden_con rows
    int N    = in_sizes[3] / 256;    // 50000 nodes
    int nrel = in_sizes[9];          // 500*64

    int t64  = nmem / 16;            // 8192 row-tiles
    int t256 = N / 16;               // 3125 row-tiles
    int g64  = t64 / 8;              // 1024 blocks: 4 waves x 2 tiles each
    int g256 = 800;                  // 3200 half-waves, ~2 tiles each

    unsigned short* hc  = (unsigned short*)d_ws;
    unsigned short* hu  = hc + (size_t)nmem * D;
    unsigned short* rb  = hu + (size_t)N * D;
    unsigned short* Wcp = rb + nrel;
    unsigned short* Wup = Wcp + 4096;
    unsigned short* wsh = Wup + 16384;
    unsigned short* fbh = wsh + 8 * D;

    prep<<<64, 256, 0, stream>>>(Wc, Wu, relt, wsm, fb, Wcp, Wup, rb, wsh, fbh,
                                 out, out_size, nrel);
    proj_fused<<<g256 + g64, 256, 0, stream>>>(hcon, Wcp, bc, hun, Wup, bu,
                                               hc, hu, t64, t256, g64, g256);
    edge_kernel<<<S / 8, 256, 0, stream>>>(natt, edges, ey, hc, hu, rb,
                                           wsh, fbh, outw, out, N);
}

// Round 6
// 192.999 us; speedup vs baseline: 1.1695x; 1.0175x over previous
//
#include <hip/hip_runtime.h>
#include <hip/hip_bf16.h>
#include <hip/hip_fp16.h>

#define D 64
#define KPER 20

typedef __attribute__((ext_vector_type(8))) short short8;
typedef __attribute__((ext_vector_type(4))) float floatx4;

__device__ __forceinline__ unsigned short f2bfu(float x) {
    __hip_bfloat16 h = __float2bfloat16(x);
    return *reinterpret_cast<unsigned short*>(&h);
}
// f16 bits (tables are f16: 3 more mantissa bits than bf16 AND enables v_pk_* math)
__device__ __forceinline__ unsigned short f2hu(float x) {
    __half h = __float2half(x);
    return *reinterpret_cast<unsigned short*>(&h);
}
union UH2 { unsigned u; __half2 h; };
__device__ __forceinline__ __half2 u2h2(unsigned u) { UH2 x; x.u = u; return x.h; }
__device__ __forceinline__ unsigned pick4(uint4 v, int p) {
    return p == 0 ? v.x : p == 1 ? v.y : p == 2 ? v.z : v.w;   // p is compile-time under unroll
}

// HW packed f32->bf16 convert (RNE): src0 -> bits[15:0], src1 -> bits[31:16]
__device__ __forceinline__ unsigned cvt2bf(float lo, float hi) {
    unsigned r;
    asm("v_cvt_pk_bf16_f32 %0, %1, %2" : "=v"(r) : "v"(lo), "v"(hi));
    return r;
}

// guaranteed-available packed f16 max (avoid header-version-dependent __hmax2)
__device__ __forceinline__ __half2 pk_max(__half2 a, __half2 b) {
    __half2 r;
    asm("v_pk_max_f16 %0, %1, %2" : "=v"(r) : "v"(a), "v"(b));
    return r;
}

__device__ __forceinline__ float fast_tanh(float x) {
    float xc = fminf(fmaxf(x, -15.f), 15.f);
    float e = __expf(2.f * xc);
    return 1.f - 2.f * __builtin_amdgcn_rcpf(1.f + e);
}

// ---- DPP reductions (VALU pipe) ----------------------------------------
template<int CTRL>
__device__ __forceinline__ float dpp_add(float x) {
    int t = __builtin_amdgcn_update_dpp(0, __float_as_int(x), CTRL, 0xf, 0xf, true);
    return x + __int_as_float(t);
}
template<int CTRL>
__device__ __forceinline__ float dpp_max(float x) {
    int xi = __float_as_int(x);
    int t = __builtin_amdgcn_update_dpp(xi, xi, CTRL, 0xf, 0xf, false);
    return fmaxf(x, __int_as_float(t));
}
__device__ __forceinline__ float wave_sum_b(float x) {
    x = dpp_add<0x111>(x); x = dpp_add<0x112>(x);
    x = dpp_add<0x114>(x); x = dpp_add<0x118>(x);
    x = dpp_add<0x142>(x); x = dpp_add<0x143>(x);
    return __int_as_float(__builtin_amdgcn_readlane(__float_as_int(x), 63));
}
__device__ __forceinline__ float wave_max_b(float x) {
    x = dpp_max<0x111>(x); x = dpp_max<0x112>(x);
    x = dpp_max<0x114>(x); x = dpp_max<0x118>(x);
    x = dpp_max<0x142>(x); x = dpp_max<0x143>(x);
    return __int_as_float(__builtin_amdgcn_readlane(__float_as_int(x), 63));
}
// sum over each 8-lane subgroup; result lands at lanes 7 and 15 of each
// 16-lane DPP row (shr1+shr2+shr4 with bound_ctrl=0-fill: lane7=sum 0..7,
// lane15=sum 8..15).
__device__ __forceinline__ float row8_sum(float x) {
    x = dpp_add<0x111>(x); x = dpp_add<0x112>(x);
    x = dpp_add<0x114>(x);
    return x;
}

// ---- prep: repack W into fragment-major bf16, convert rel/ws/fb to f16,
// zero out. MFMA weights stay bf16; gather tables go f16. ----------------
__global__ __launch_bounds__(256) void prep(
        const float* __restrict__ Wc, const float* __restrict__ Wu,
        const float* __restrict__ relf, const float* __restrict__ wsf,
        const float* __restrict__ fbf,
        unsigned short* __restrict__ Wcp, unsigned short* __restrict__ Wup,
        unsigned short* __restrict__ relb, unsigned short* __restrict__ wsh,
        unsigned short* __restrict__ fbh, float* __restrict__ outz,
        int nout, int nrel) {
    int tid = blockIdx.x * 256 + threadIdx.x;
    int nth = gridDim.x * 256;
    for (int i = tid; i < 4 * 2 * 64 * 8; i += nth) {
        int j = i & 7, lane = (i >> 3) & 63, f = i >> 9;
        int ct = f >> 1, kt = f & 1;
        int m = lane & 15, quad = lane >> 4;
        Wcp[i] = f2bfu(Wc[(kt * 32 + quad * 8 + j) * 64 + ct * 16 + m]);
    }
    for (int i = tid; i < 4 * 8 * 64 * 8; i += nth) {
        int j = i & 7, lane = (i >> 3) & 63, f = i >> 9;
        int ct = f >> 3, kt = f & 7;
        int m = lane & 15, quad = lane >> 4;
        Wup[i] = f2bfu(Wu[(kt * 32 + quad * 8 + j) * 64 + ct * 16 + m]);
    }
    for (int i = tid; i < nrel; i += nth) relb[i] = f2hu(relf[i]);
    for (int i = tid; i < 8 * D; i += nth) wsh[i] = f2hu(wsf[i]);
    for (int i = tid; i < D; i += nth) fbh[i] = f2hu(fbf[i]);
    for (int i = tid; i < nout; i += nth) outz[i] = 0.0f;
}

// ---- K=64 projection, pair of row-tiles per wave; packed-W frag init ---
__device__ __forceinline__ void proj64_pair(const float* __restrict__ h,
        const unsigned short* __restrict__ Wp, const float* __restrict__ b,
        unsigned short* __restrict__ out, int rt0) {
    constexpr int K = 64, KT = 2, CTN = 4;
    int lane = threadIdx.x & 63;
    int m = lane & 15, quad = lane >> 4;
    short8 bfr[CTN][KT];
    #pragma unroll
    for (int ct = 0; ct < CTN; ++ct)
        #pragma unroll
        for (int kt = 0; kt < KT; ++kt)
            bfr[ct][kt] = *(const short8*)(Wp + (((ct * 2 + kt) * 64 + lane) << 3));
    float bv[CTN];
    #pragma unroll
    for (int ct = 0; ct < CTN; ++ct) bv[ct] = b[ct * 16 + m];
    int rt1 = rt0 + 1;
    const float* hrow0 = h + (size_t)(rt0 * 16 + m) * K + quad * 8;
    const float* hrow1 = h + (size_t)(rt1 * 16 + m) * K + quad * 8;
    floatx4 a0[KT][2], a1[KT][2];
    #pragma unroll
    for (int kt = 0; kt < KT; ++kt) {
        a0[kt][0] = *(const floatx4*)(hrow0 + kt * 32);
        a0[kt][1] = *(const floatx4*)(hrow0 + kt * 32 + 4);
        a1[kt][0] = *(const floatx4*)(hrow1 + kt * 32);
        a1[kt][1] = *(const floatx4*)(hrow1 + kt * 32 + 4);
    }
    #pragma unroll
    for (int t = 0; t < 2; ++t) {
        floatx4 (*ar)[2] = t ? a1 : a0;
        int rt = t ? rt1 : rt0;
        floatx4 acc[CTN];
        #pragma unroll
        for (int ct = 0; ct < CTN; ++ct) acc[ct] = floatx4{0.f, 0.f, 0.f, 0.f};
        #pragma unroll
        for (int kt = 0; kt < KT; ++kt) {
            union { uint4 u; short8 s; } cc;
            cc.u.x = cvt2bf(ar[kt][0][0], ar[kt][0][1]);
            cc.u.y = cvt2bf(ar[kt][0][2], ar[kt][0][3]);
            cc.u.z = cvt2bf(ar[kt][1][0], ar[kt][1][1]);
            cc.u.w = cvt2bf(ar[kt][1][2], ar[kt][1][3]);
            short8 af = cc.s;
            #pragma unroll
            for (int ct = 0; ct < CTN; ++ct)
                acc[ct] = __builtin_amdgcn_mfma_f32_16x16x32_bf16(af, bfr[ct][kt], acc[ct], 0, 0, 0);
        }
        #pragma unroll
        for (int ct = 0; ct < CTN; ++ct) {
            int col = ct * 16 + m;
            #pragma unroll
            for (int reg = 0; reg < 4; ++reg) {
                int row = rt * 16 + quad * 4 + reg;
                out[(size_t)row * 64 + col] = f2hu(fast_tanh(acc[ct][reg] + bv[ct]));
            }
        }
    }
}

// ---- K=256 projection (CTN=2 column-halves); packed-W frag init --------
__device__ __forceinline__ void proj256_body(const float* __restrict__ h,
        const unsigned short* __restrict__ Wp, const float* __restrict__ b,
        unsigned short* __restrict__ out, int ct0, int rt0, int rtstride, int ntiles) {
    constexpr int K = 256, KT = 8, CTN = 2;
    int lane = threadIdx.x & 63;
    int m = lane & 15, quad = lane >> 4;
    short8 bfr[CTN][KT];
    #pragma unroll
    for (int ct = 0; ct < CTN; ++ct)
        #pragma unroll
        for (int kt = 0; kt < KT; ++kt)
            bfr[ct][kt] = *(const short8*)(Wp + ((((ct0 + ct) * 8 + kt) * 64 + lane) << 3));
    float bv[CTN];
    #pragma unroll
    for (int ct = 0; ct < CTN; ++ct) bv[ct] = b[(ct0 + ct) * 16 + m];
    for (int rt = rt0; rt < ntiles; rt += rtstride) {
        floatx4 acc[CTN];
        #pragma unroll
        for (int ct = 0; ct < CTN; ++ct) acc[ct] = floatx4{0.f, 0.f, 0.f, 0.f};
        const float* hrow = h + (size_t)(rt * 16 + m) * K + quad * 8;
        #pragma unroll
        for (int kt = 0; kt < KT; ++kt) {
            floatx4 v0 = *(const floatx4*)(hrow + kt * 32);
            floatx4 v1 = *(const floatx4*)(hrow + kt * 32 + 4);
            union { uint4 u; short8 s; } cc;
            cc.u.x = cvt2bf(v0[0], v0[1]);
            cc.u.y = cvt2bf(v0[2], v0[3]);
            cc.u.z = cvt2bf(v1[0], v1[1]);
            cc.u.w = cvt2bf(v1[2], v1[3]);
            short8 af = cc.s;
            #pragma unroll
            for (int ct = 0; ct < CTN; ++ct)
                acc[ct] = __builtin_amdgcn_mfma_f32_16x16x32_bf16(af, bfr[ct][kt], acc[ct], 0, 0, 0);
        }
        #pragma unroll
        for (int ct = 0; ct < CTN; ++ct) {
            int col = (ct0 + ct) * 16 + m;
            #pragma unroll
            for (int reg = 0; reg < 4; ++reg) {
                int row = rt * 16 + quad * 4 + reg;
                out[(size_t)row * 64 + col] = f2hu(fast_tanh(acc[ct][reg] + bv[ct]));
            }
        }
    }
}

// Fused proj: proj256 blocks FIRST (long-running -> start at t=0), then
// proj64. W-frag init is coalesced dwordx4 from prep's packed layout.
__global__ __launch_bounds__(256) void proj_fused(
        const float* __restrict__ hcon, const unsigned short* __restrict__ Wcp,
        const float* __restrict__ bc,
        const float* __restrict__ hun, const unsigned short* __restrict__ Wup,
        const float* __restrict__ bu,
        unsigned short* __restrict__ hc, unsigned short* __restrict__ hu,
        int t64, int t256, int g64, int g256) {
    int bid = blockIdx.x;
    int w = threadIdx.x >> 6;
    if (bid < g256) {
        int wid = bid * 4 + w;
        int half = wid & 1;                 // fixed per wave -> B-frags loaded once
        proj256_body(hun, Wup, bu, hu, half * 2, wid >> 1, g256 * 2, t256);
    } else {
        int wid = (bid - g256) * 4 + w;
        proj64_pair(hcon, Wcp, bc, hc, wid * 2);
    }
}

// Packed-f16 F-layer for ONE edge; each lane owns 8 features (4 __half2),
// gathered as ONE dwordx4 per feature table (8 lanes x 16B = full 128B row).
__device__ __forceinline__ float edge_acc8(
        uint4 G0, uint4 G2, uint4 G3, uint4 G4, uint4 F1,
        const uint4* __restrict__ wk4, uint4 fb4,
        floatx4 ow0, floatx4 ow1, __half2 z2) {
    float acc = 0.f;
    #pragma unroll
    for (int p = 0; p < 4; ++p) {
        __half2 F0 = u2h2(pick4(G0, p));
        __half2 F2 = u2h2(pick4(G2, p));
        __half2 F3 = u2h2(pick4(G3, p));
        __half2 F4 = u2h2(pick4(G4, p));
        __half2 f1 = u2h2(pick4(F1, p));
        __half2 fb2 = u2h2(pick4(fb4, p));
        __half2 w0 = u2h2(pick4(wk4[0], p));
        __half2 w1 = u2h2(pick4(wk4[1], p));
        __half2 w2 = u2h2(pick4(wk4[2], p));
        __half2 w3 = u2h2(pick4(wk4[3], p));
        __half2 w4 = u2h2(pick4(wk4[4], p));
        __half2 w5 = u2h2(pick4(wk4[5], p));
        __half2 w6 = u2h2(pick4(wk4[6], p));
        __half2 w7 = u2h2(pick4(wk4[7], p));
        __half2 t1 = __hfma2(F2, w1, w0);
        __half2 t2 = __hfma2(F2, w5, w4);
        __half2 t3 = __hfma2(F2, w3, w2);
        __half2 t4 = __hfma2(F2, w7, w6);
        __half2 uu = __hfma2(F0, t1, __hmul2(f1, t2));
        __half2 vv = __hfma2(F0, t3, __hmul2(f1, t4));
        __half2 od = __hfma2(F3, uu, __hfma2(F4, vv, fb2));
        __half2 r  = pk_max(od, z2);
        float2 rf  = __half22float2(r);
        float owa = (p < 2) ? ow0[2 * p]     : ow1[2 * p - 4];
        float owb = (p < 2) ? ow0[2 * p + 1] : ow1[2 * p - 3];
        acc = fmaf(rf.x, owa, fmaf(rf.y, owb, acc));
    }
    return acc;
}

// TWO sorted vi-segments per wave. WIDE-GATHER layout: 8 lanes x dwordx4
// per feature row (was 16 lanes x dwordx2) -> one VMEM instruction covers
// 8 edges, 12 gathers/segment instead of 21. R4/R5 falsified the latency-
// depth theory (pipeline + VGPR headroom both null); this targets the
// remaining candidate: per-CU outstanding-request throughput. Same bytes,
// same FLOPs, ~40% fewer scattered requests.
__global__ __launch_bounds__(256, 3) void edge_kernel(
        const float* __restrict__ natt, const int* __restrict__ edges,
        const float* __restrict__ ey, const unsigned short* __restrict__ hc,
        const unsigned short* __restrict__ hu, const unsigned short* __restrict__ relt,
        const unsigned short* __restrict__ wsh, const unsigned short* __restrict__ fbh,
        const float* __restrict__ outw, float* __restrict__ out, int N) {
    int lane = threadIdx.x & 63;
    int g8 = lane >> 3, sub8 = lane & 7;
    int wid = blockIdx.x * 4 + (threadIdx.x >> 6);
    long baseA = (long)(wid * 2) * KPER;
    long baseB = baseA + KPER;
    const int* ebA = edges + baseA * 8;
    const int* ebB = edges + baseB * 8;

    // ---- metadata: per pass t, group g8 handles edge t*8+g8 (clamped) ----
    int2 h0A = *(const int2*)ebA;                 // (eg, vi)
    int2 h0B = *(const int2*)ebB;
    int2 m23A[3], m67A[3], m23B[3], m67B[3];      // (vj,rel), (e2vi,e2vj)
    #pragma unroll
    for (int t = 0; t < 3; ++t) {
        int e = t * 8 + g8; e = (e < KPER) ? e : (KPER - 1);
        m23A[t] = *(const int2*)(ebA + e * 8 + 2);
        m67A[t] = *(const int2*)(ebA + e * 8 + 6);
        m23B[t] = *(const int2*)(ebB + e * 8 + 2);
        m67B[t] = *(const int2*)(ebB + e * 8 + 6);
    }
    // atomic-tail operands, off the critical path
    int myvjA = 0, myvjB = 0; float eyA = 0.f, eyB = 0.f;
    if (lane < KPER) {
        myvjA = ebA[lane * 8 + 2];
        myvjB = ebB[lane * 8 + 2];
        eyA = ey[baseA + lane];
        eyB = ey[baseB + lane];
    }
    int egA = __builtin_amdgcn_readfirstlane(h0A.x);
    int viA = __builtin_amdgcn_readfirstlane(h0A.y);
    int egB = __builtin_amdgcn_readfirstlane(h0B.x);
    int viB = __builtin_amdgcn_readfirstlane(h0B.y);

    // ---- wide gathers: 4 per pass per segment (uint4 = 16B/lane) ---------
    uint4 GA0[3], GA2[3], GA3[3], GA4[3];
    #pragma unroll
    for (int t = 0; t < 3; ++t) {
        GA0[t] = *(const uint4*)(hc   + (size_t)m67A[t].x * D + sub8 * 8);
        GA2[t] = *(const uint4*)(relt + (size_t)m23A[t].y * D + sub8 * 8);
        GA3[t] = *(const uint4*)(hc   + (size_t)m67A[t].y * D + sub8 * 8);
        GA4[t] = *(const uint4*)(hu   + (size_t)m23A[t].x * D + sub8 * 8);
    }
    uint4 F1A = *(const uint4*)(hu + (size_t)viA * D + sub8 * 8);
    uint4 GB0[3], GB2[3], GB3[3], GB4[3];
    #pragma unroll
    for (int t = 0; t < 3; ++t) {
        GB0[t] = *(const uint4*)(hc   + (size_t)m67B[t].x * D + sub8 * 8);
        GB2[t] = *(const uint4*)(relt + (size_t)m23B[t].y * D + sub8 * 8);
        GB3[t] = *(const uint4*)(hc   + (size_t)m67B[t].y * D + sub8 * 8);
        GB4[t] = *(const uint4*)(hu   + (size_t)m23B[t].x * D + sub8 * 8);
    }
    uint4 F1B = *(const uint4*)(hu + (size_t)viB * D + sub8 * 8);
    float naA = natt[(size_t)egA * N + viA];
    float naB = natt[(size_t)egB * N + viB];

    // ---- per-lane constants (f16 ws/fb; f32 out_w), 8 features/lane ------
    uint4 wk4[8];
    #pragma unroll
    for (int k = 0; k < 8; ++k) wk4[k] = *(const uint4*)(wsh + k * D + sub8 * 8);
    uint4 fb4 = *(const uint4*)(fbh + sub8 * 8);
    floatx4 ow0 = *(const floatx4*)(outw + sub8 * 8);
    floatx4 ow1 = *(const floatx4*)(outw + sub8 * 8 + 4);
    __half2 z2 = __float2half2_rn(0.f);

    // ---- segment A: 3 passes x 8 edges, row8 reduce, softmax, scatter ----
    float mylA = -INFINITY, mylB = -INFINITY;
    #pragma unroll
    for (int t = 0; t < 3; ++t) {
        float acc = edge_acc8(GA0[t], GA2[t], GA3[t], GA4[t], F1A, wk4, fb4, ow0, ow1, z2);
        float rs = row8_sum(acc);                       // sums at lanes 8g+7
        float tot = __shfl(rs, ((lane & 7) << 3) + 7);  // edge lane = lane
        mylA = ((lane >> 3) == t && lane < KPER) ? tot : mylA;
    }
    float mxA = wave_max_b(mylA);
    float exA = __expf(mylA - mxA);
    float denA = wave_sum_b(exA);
    if (lane < KPER) {
        float tv = (exA / denA) * naA * eyA;
        atomicAdd(out + (size_t)egA * N + myvjA, tv);
    }
    // ---- segment B -------------------------------------------------------
    #pragma unroll
    for (int t = 0; t < 3; ++t) {
        float acc = edge_acc8(GB0[t], GB2[t], GB3[t], GB4[t], F1B, wk4, fb4, ow0, ow1, z2);
        float rs = row8_sum(acc);
        float tot = __shfl(rs, ((lane & 7) << 3) + 7);
        mylB = ((lane >> 3) == t && lane < KPER) ? tot : mylB;
    }
    float mxB = wave_max_b(mylB);
    float exB = __expf(mylB - mxB);
    float denB = wave_sum_b(exB);
    if (lane < KPER) {
        float tv = (exB / denB) * naB * eyB;
        atomicAdd(out + (size_t)egB * N + myvjB, tv);
    }
}

extern "C" void kernel_launch(void* const* d_in, const int* in_sizes, int n_in,
                              void* d_out, int out_size, void* d_ws, size_t ws_size,
                              hipStream_t stream) {
    const float* natt = (const float*)d_in[0];
    const int*   edges = (const int*)d_in[1];
    const float* ey   = (const float*)d_in[2];
    const float* hun  = (const float*)d_in[3];
    const float* hcon = (const float*)d_in[4];
    const float* Wc   = (const float*)d_in[5];
    const float* bc   = (const float*)d_in[6];
    const float* Wu   = (const float*)d_in[7];
    const float* bu   = (const float*)d_in[8];
    const float* relt = (const float*)d_in[9];
    const float* wsm  = (const float*)d_in[10];
    const float* fb   = (const float*)d_in[11];
    const float* outw = (const float*)d_in[12];
    float* out = (float*)d_out;

    int E    = in_sizes[2];          // 400000 edges
    int S    = E / KPER;             // 20000 sorted vi segments
    int nmem = in_sizes[4] / D;      // 131072 hidden_con rows
    int N    = in_sizes[3] / 256;    // 50000 nodes
    int nrel = in_sizes[9];          // 500*64

    int t64  = nmem / 16;            // 8192 row-tiles
    int t256 = N / 16;               // 3125 row-tiles
    int g64  = t64 / 8;              // 1024 blocks: 4 waves x 2 tiles each
    int g256 = 800;                  // 3200 half-waves, ~2 tiles each

    unsigned short* hc  = (unsigned short*)d_ws;
    unsigned short* hu  = hc + (size_t)nmem * D;
    unsigned short* rb  = hu + (size_t)N * D;
    unsigned short* Wcp = rb + nrel;
    unsigned short* Wup = Wcp + 4096;
    unsigned short* wsh = Wup + 16384;
    unsigned short* fbh = wsh + 8 * D;

    prep<<<64, 256, 0, stream>>>(Wc, Wu, relt, wsm, fb, Wcp, Wup, rb, wsh, fbh,
                                 out, out_size, nrel);
    proj_fused<<<g256 + g64, 256, 0, stream>>>(hcon, Wcp, bc, hun, Wup, bu,
                                               hc, hu, t64, t256, g64, g256);
    edge_kernel<<<S / 8, 256, 0, stream>>>(natt, edges, ey, hc, hu, rb,
                                           wsh, fbh, outw, out, N);
}